// Round 2
// baseline (259.704 us; speedup 1.0000x reference)
//
#include <hip/hip_runtime.h>
#include <hip/hip_bf16.h>
#include <cstdint>

typedef unsigned short u16;
typedef __attribute__((ext_vector_type(8))) short bf16x8;
typedef __attribute__((ext_vector_type(4))) float f32x4;

#define S_LEN 1024
#define BATCH 8
#define DMODEL 256
#define NHEAD 8
#define HDIM 32
#define DFF 1024
#define NROWS (S_LEN * BATCH)   // 8192

static __device__ __forceinline__ u16 f2b(float f) {
    union { float f; unsigned u; } x{f};
    unsigned r = (x.u + 0x7fffu + ((x.u >> 16) & 1u)) >> 16;
    return (u16)r;
}

// ---------------------------------------------------------------------------
// Weight conversion: f32 -> bf16, q-scale folded into Wq rows and bq.
// ---------------------------------------------------------------------------
__global__ __launch_bounds__(256) void convert_weights(
    const float* __restrict__ ipw, const float* __restrict__ outw,
    const float* __restrict__ w1, const float* __restrict__ w2,
    const float* __restrict__ ipb,
    u16* __restrict__ wqkv, u16* __restrict__ wout,
    u16* __restrict__ w1b, u16* __restrict__ w2b, float* __restrict__ bq)
{
    const float s = 0.17677669529663689f; // 1/sqrt(32)
    int i = blockIdx.x * 256 + threadIdx.x;
    if (i < 196608) {
        float v = ipw[i];
        if (i < 65536) v *= s;
        wqkv[i] = f2b(v);
    } else if (i < 262144) {
        wout[i - 196608] = f2b(outw[i - 196608]);
    } else if (i < 524288) {
        w1b[i - 262144] = f2b(w1[i - 262144]);
    } else if (i < 786432) {
        w2b[i - 524288] = f2b(w2[i - 524288]);
    }
    if (i < 768) bq[i] = ipb[i] * (i < 256 ? s : 1.0f);
}

// ---------------------------------------------------------------------------
// LayerNorm (LN1): one wave per row of 256; outputs f32 and bf16 copies.
// ---------------------------------------------------------------------------
__global__ __launch_bounds__(256) void ln_kernel(
    const float* __restrict__ in, const float* __restrict__ g,
    const float* __restrict__ be, float* __restrict__ of, u16* __restrict__ ob)
{
    const int w = threadIdx.x >> 6, l = threadIdx.x & 63;
    const int row = blockIdx.x * 4 + w;
    const float4 v = *(const float4*)(in + (size_t)row * DMODEL + l * 4);
    float s = v.x + v.y + v.z + v.w;
    #pragma unroll
    for (int o = 32; o; o >>= 1) s += __shfl_xor(s, o);
    const float mu = s * (1.0f / DMODEL);
    const float dx = v.x - mu, dy = v.y - mu, dz = v.z - mu, dw = v.w - mu;
    float sq = dx * dx + dy * dy + dz * dz + dw * dw;
    #pragma unroll
    for (int o = 32; o; o >>= 1) sq += __shfl_xor(sq, o);
    const float rs = rsqrtf(sq * (1.0f / DMODEL) + 1e-5f);
    const float4 gv = *(const float4*)(g + l * 4);
    const float4 bv = *(const float4*)(be + l * 4);
    const float r0 = dx * rs * gv.x + bv.x;
    const float r1 = dy * rs * gv.y + bv.y;
    const float r2 = dz * rs * gv.z + bv.z;
    const float r3 = dw * rs * gv.w + bv.w;
    *(float4*)(of + (size_t)row * DMODEL + l * 4) = make_float4(r0, r1, r2, r3);
    uint2 pk;
    pk.x = (unsigned)f2b(r0) | ((unsigned)f2b(r1) << 16);
    pk.y = (unsigned)f2b(r2) | ((unsigned)f2b(r3) << 16);
    *(uint2*)(ob + (size_t)row * DMODEL + l * 4) = pk;
}

// ---------------------------------------------------------------------------
// Barrier-free GEMM, transposed accumulator: C[M,N] = A[M,K] @ Bw[N,K]^T.
// mfma(B_frag, A_frag) -> D[col_local][xrow]: lane owns row (l&15),
// 4 consecutive cols (g*4+r) per n-fragment -> packed epilogue stores.
// MODE 0: +bias -> bf16. MODE 2: +bias, relu -> bf16. MODE 3: +bias+resid -> f32.
// block = 256 thr (4 waves x 16 rows); grid (M/64, N/64). No LDS, no barriers.
// ---------------------------------------------------------------------------
template <int MODE>
__global__ __launch_bounds__(256) void gemm_nt(
    const u16* __restrict__ A, const u16* __restrict__ Bw,
    const float* __restrict__ bias, const float* __restrict__ resid,
    float* __restrict__ outf, u16* __restrict__ outb,
    int N, int K)
{
    const int tid = threadIdx.x, w = tid >> 6, l = tid & 63;
    const int g = l >> 4, q = l & 15;
    const int row = blockIdx.x * 64 + w * 16 + q;
    const int nbase = blockIdx.y * 64;
    f32x4 acc[4] = {{0,0,0,0},{0,0,0,0},{0,0,0,0},{0,0,0,0}};
    const u16* Arow = A + (size_t)row * K + g * 8;
    const u16* Brow = Bw + (size_t)(nbase + q) * K + g * 8;

    #pragma unroll 2
    for (int kk = 0; kk < K; kk += 32) {
        const bf16x8 af = *(const bf16x8*)(Arow + kk);
        #pragma unroll
        for (int n = 0; n < 4; ++n) {
            const bf16x8 bf = *(const bf16x8*)(Brow + (size_t)n * 16 * K + kk);
            acc[n] = __builtin_amdgcn_mfma_f32_16x16x32_bf16(bf, af, acc[n], 0, 0, 0);
        }
    }

    #pragma unroll
    for (int n = 0; n < 4; ++n) {
        const int col = nbase + n * 16 + g * 4;
        const float4 bv = *(const float4*)(bias + col);
        float v0 = acc[n][0] + bv.x, v1 = acc[n][1] + bv.y;
        float v2 = acc[n][2] + bv.z, v3 = acc[n][3] + bv.w;
        if (MODE == 0 || MODE == 2) {
            if (MODE == 2) {
                v0 = fmaxf(v0, 0.f); v1 = fmaxf(v1, 0.f);
                v2 = fmaxf(v2, 0.f); v3 = fmaxf(v3, 0.f);
            }
            uint2 pk;
            pk.x = (unsigned)f2b(v0) | ((unsigned)f2b(v1) << 16);
            pk.y = (unsigned)f2b(v2) | ((unsigned)f2b(v3) << 16);
            *(uint2*)(outb + (size_t)row * N + col) = pk;
        } else {
            const float4 rv = *(const float4*)(resid + (size_t)row * N + col);
            *(float4*)(outf + (size_t)row * N + col) =
                make_float4(v0 + rv.x, v1 + rv.y, v2 + rv.z, v3 + rv.w);
        }
    }
}

// ---------------------------------------------------------------------------
// V transpose: qkv cols [512,768) -> Vt [B*H, HD, S] bf16 (coalesced both sides)
// grid (S/64, B*H), 256 thr.
// ---------------------------------------------------------------------------
__global__ __launch_bounds__(256) void transpose_v(
    const u16* __restrict__ qkv, u16* __restrict__ Vt)
{
    __shared__ u16 sT[32][68];
    const int st = blockIdx.x, bh = blockIdx.y;
    const int b = bh >> 3, h = bh & 7;
    const int t = threadIdx.x;
    const int srow = t >> 2, seg = t & 3;
    uint4 v = *(const uint4*)(qkv +
        ((size_t)((st * 64 + srow) * 8 + b)) * 768 + 512 + h * 32 + seg * 8);
    const u16* pv = (const u16*)&v;
    #pragma unroll
    for (int e = 0; e < 8; ++e) sT[seg * 8 + e][srow] = pv[e];
    __syncthreads();
    const int d = t >> 3, chunk = t & 7;
    u16 o[8];
    #pragma unroll
    for (int e = 0; e < 8; ++e) o[e] = sT[d][chunk * 8 + e];
    *(uint4*)(Vt + ((size_t)bh * 32 + d) * S_LEN + st * 64 + chunk * 8) = *(uint4*)o;
}

// ---------------------------------------------------------------------------
// Flash attention, swapped operands throughout; lane-local softmax state.
// QK^T: mfma(K,Q) -> D[k_local][q]; bias add = float4 -> f32x4 1:1.
// PV:   mfma(Vt,P) -> D[d_local][q]; rescale & 1/lsum lane-local.
// No __syncthreads; only per-wave P LDS buffer (XOR-swizzled).
// grid (S/64, B*H), 256 thr (4 independent waves x 16 q-rows).
// ---------------------------------------------------------------------------
__global__ __launch_bounds__(256) void attn_kernel(
    const u16* __restrict__ qkv, const u16* __restrict__ Vt,
    const float* __restrict__ bias, u16* __restrict__ ctx)
{
    __shared__ u16 sP[4][16 * 64];
    const int tid = threadIdx.x, w = tid >> 6, l = tid & 63;
    const int g = l >> 4, q = l & 15;
    const int bh = blockIdx.y, b = bh >> 3, h = bh & 7;
    const int qrow = blockIdx.x * 64 + w * 16 + q;

    const bf16x8 qf = *(const bf16x8*)(qkv + ((size_t)qrow * 8 + b) * 768 + h * 32 + g * 8);
    const u16* Kp = qkv + (size_t)b * 768 + 256 + h * 32 + g * 8;     // + krow*6144
    const u16* Vp = Vt + ((size_t)bh * 32 + q) * S_LEN + g * 8;       // + jg*16*1024
    const float* brow = bias + ((size_t)bh * S_LEN + qrow) * S_LEN;
    u16* Pw = sP[w];
    const int swz = (q & 7) << 4;

    f32x4 ctxa[2] = {{0,0,0,0},{0,0,0,0}};
    float m = -1e30f, lsum = 0.f;

    for (int kt = 0; kt < S_LEN / 64; ++kt) {
        // bias prefetch (maps 1:1 onto D fragments)
        float4 bv[4];
        #pragma unroll
        for (int n = 0; n < 4; ++n)
            bv[n] = *(const float4*)(brow + kt * 64 + n * 16 + g * 4);

        // S^T tile: D[k_local = n*16+g*4+r][q]
        f32x4 sc[4];
        #pragma unroll
        for (int n = 0; n < 4; ++n) {
            const bf16x8 kf = *(const bf16x8*)(Kp + (size_t)(kt * 64 + n * 16 + q) * 6144);
            f32x4 z = {0, 0, 0, 0};
            sc[n] = __builtin_amdgcn_mfma_f32_16x16x32_bf16(kf, qf, z, 0, 0, 0);
        }
        #pragma unroll
        for (int n = 0; n < 4; ++n) {
            sc[n][0] += bv[n].x; sc[n][1] += bv[n].y;
            sc[n][2] += bv[n].z; sc[n][3] += bv[n].w;
        }

        // online softmax, lane-local (q = l&15); reduce across g via 2 shfl
        float mx = sc[0][0];
        #pragma unroll
        for (int n = 0; n < 4; ++n)
            #pragma unroll
            for (int r = 0; r < 4; ++r) mx = fmaxf(mx, sc[n][r]);
        mx = fmaxf(mx, __shfl_xor(mx, 16));
        mx = fmaxf(mx, __shfl_xor(mx, 32));
        const float mn = fmaxf(m, mx);
        const float corr = __expf(m - mn);
        float su = 0.f;
        u16 pb[16];
        #pragma unroll
        for (int n = 0; n < 4; ++n)
            #pragma unroll
            for (int r = 0; r < 4; ++r) {
                const float pv = __expf(sc[n][r] - mn);
                su += pv;
                pb[n * 4 + r] = f2b(pv);
            }
        su += __shfl_xor(su, 16);
        su += __shfl_xor(su, 32);
        lsum = lsum * corr + su;
        m = mn;
        #pragma unroll
        for (int jg = 0; jg < 2; ++jg)
            #pragma unroll
            for (int r = 0; r < 4; ++r) ctxa[jg][r] *= corr;

        // P -> per-wave LDS (packed b64, XOR-swizzled rows)
        #pragma unroll
        for (int n = 0; n < 4; ++n) {
            uint2 pk;
            pk.x = (unsigned)pb[n * 4] | ((unsigned)pb[n * 4 + 1] << 16);
            pk.y = (unsigned)pb[n * 4 + 2] | ((unsigned)pb[n * 4 + 3] << 16);
            *(uint2*)((char*)Pw + q * 128 + ((n * 32 + g * 8) ^ swz)) = pk;
        }

        // ctx^T += V^T-rows x P : D[d_local][q]
        #pragma unroll
        for (int ks = 0; ks < 2; ++ks) {
            const bf16x8 pf = *(const bf16x8*)((char*)Pw + q * 128 + ((ks * 64 + g * 16) ^ swz));
            #pragma unroll
            for (int jg = 0; jg < 2; ++jg) {
                const bf16x8 vf = *(const bf16x8*)(Vp + (size_t)jg * 16 * S_LEN + kt * 64 + ks * 32);
                ctxa[jg] = __builtin_amdgcn_mfma_f32_16x16x32_bf16(vf, pf, ctxa[jg], 0, 0, 0);
            }
        }
    }

    // write ctx -> [S,B,D] bf16 (lane-local 1/lsum; 4 consecutive d per jg)
    const float inv = 1.0f / lsum;
    #pragma unroll
    for (int jg = 0; jg < 2; ++jg) {
        uint2 pk;
        pk.x = (unsigned)f2b(ctxa[jg][0] * inv) | ((unsigned)f2b(ctxa[jg][1] * inv) << 16);
        pk.y = (unsigned)f2b(ctxa[jg][2] * inv) | ((unsigned)f2b(ctxa[jg][3] * inv) << 16);
        *(uint2*)(ctx + ((size_t)qrow * 8 + b) * DMODEL + h * 32 + jg * 16 + g * 4) = pk;
    }
}

// ---------------------------------------------------------------------------
// Fused out-proj + residual(xf) + LayerNorm2 -> yf (f32), yb (bf16).
// One wave per 16 rows, full N=256 in-register (acc[16]); LN per row needs
// only 2 shfl_xor (row cols live in lanes q, q+16, q+32, q+48).
// block = 64 thr (1 wave), grid = NROWS/16 = 512.
// ---------------------------------------------------------------------------
__global__ __launch_bounds__(64) void oproj_ln(
    const u16* __restrict__ ctx, const u16* __restrict__ wob,
    const float* __restrict__ ob, const float* __restrict__ xf,
    const float* __restrict__ g2, const float* __restrict__ be2,
    float* __restrict__ yf, u16* __restrict__ yb)
{
    const int l = threadIdx.x;
    const int g = l >> 4, q = l & 15;
    const int row = blockIdx.x * 16 + q;
    f32x4 acc[16];
    #pragma unroll
    for (int n = 0; n < 16; ++n) acc[n] = (f32x4){0, 0, 0, 0};
    const u16* Arow = ctx + (size_t)row * 256 + g * 8;
    const u16* Brow = wob + (size_t)q * 256 + g * 8;

    #pragma unroll 2
    for (int kk = 0; kk < 256; kk += 32) {
        const bf16x8 af = *(const bf16x8*)(Arow + kk);
        #pragma unroll
        for (int n = 0; n < 16; ++n) {
            const bf16x8 bf = *(const bf16x8*)(Brow + (size_t)n * 16 * 256 + kk);
            acc[n] = __builtin_amdgcn_mfma_f32_16x16x32_bf16(bf, af, acc[n], 0, 0, 0);
        }
    }

    float sum = 0.f;
    #pragma unroll
    for (int n = 0; n < 16; ++n) {
        const int col = n * 16 + g * 4;
        const float4 bv = *(const float4*)(ob + col);
        const float4 rv = *(const float4*)(xf + (size_t)row * 256 + col);
        acc[n][0] += bv.x + rv.x; acc[n][1] += bv.y + rv.y;
        acc[n][2] += bv.z + rv.z; acc[n][3] += bv.w + rv.w;
        sum += acc[n][0] + acc[n][1] + acc[n][2] + acc[n][3];
    }
    sum += __shfl_xor(sum, 16);
    sum += __shfl_xor(sum, 32);
    const float mu = sum * (1.0f / 256);
    float sq = 0.f;
    #pragma unroll
    for (int n = 0; n < 16; ++n)
        #pragma unroll
        for (int r = 0; r < 4; ++r) {
            const float d = acc[n][r] - mu;
            sq += d * d;
        }
    sq += __shfl_xor(sq, 16);
    sq += __shfl_xor(sq, 32);
    const float rs = rsqrtf(sq * (1.0f / 256) + 1e-5f);

    #pragma unroll
    for (int n = 0; n < 16; ++n) {
        const int col = n * 16 + g * 4;
        const float4 gv = *(const float4*)(g2 + col);
        const float4 b2 = *(const float4*)(be2 + col);
        const float y0 = (acc[n][0] - mu) * rs * gv.x + b2.x;
        const float y1 = (acc[n][1] - mu) * rs * gv.y + b2.y;
        const float y2 = (acc[n][2] - mu) * rs * gv.z + b2.z;
        const float y3 = (acc[n][3] - mu) * rs * gv.w + b2.w;
        *(float4*)(yf + (size_t)row * 256 + col) = make_float4(y0, y1, y2, y3);
        uint2 pk;
        pk.x = (unsigned)f2b(y0) | ((unsigned)f2b(y1) << 16);
        pk.y = (unsigned)f2b(y2) | ((unsigned)f2b(y3) << 16);
        *(uint2*)(yb + (size_t)row * 256 + col) = pk;
    }
}

// ---------------------------------------------------------------------------
extern "C" void kernel_launch(void* const* d_in, const int* in_sizes, int n_in,
                              void* d_out, int out_size, void* d_ws, size_t ws_size,
                              hipStream_t stream)
{
    const float* src  = (const float*)d_in[0];
    const float* bias = (const float*)d_in[1];
    const float* ipw  = (const float*)d_in[2];
    const float* ipb  = (const float*)d_in[3];
    const float* outw = (const float*)d_in[4];
    const float* outb = (const float*)d_in[5];
    const float* w1   = (const float*)d_in[6];
    const float* b1   = (const float*)d_in[7];
    const float* w2   = (const float*)d_in[8];
    const float* b2   = (const float*)d_in[9];
    const float* g1   = (const float*)d_in[10];
    const float* be1  = (const float*)d_in[11];
    const float* g2   = (const float*)d_in[12];
    const float* be2  = (const float*)d_in[13];

    char* p = (char*)d_ws;
    auto alloc = [&](size_t bytes) -> void* {
        void* r = (void*)p;
        p += (bytes + 255) & ~(size_t)255;
        return r;
    };
    float* xf   = (float*)alloc((size_t)NROWS * DMODEL * 4);
    u16*   xb   = (u16*)  alloc((size_t)NROWS * DMODEL * 2);
    u16*   qkv  = (u16*)  alloc((size_t)NROWS * 768 * 2);
    u16*   Vt   = (u16*)  alloc((size_t)64 * S_LEN * HDIM * 2);
    u16*   ctx  = (u16*)  alloc((size_t)NROWS * DMODEL * 2);
    float* yf   = (float*)alloc((size_t)NROWS * DMODEL * 4);
    u16*   yb   = (u16*)  alloc((size_t)NROWS * DMODEL * 2);
    u16*   hb   = (u16*)  alloc((size_t)NROWS * DFF * 2);
    u16*   wqkv = (u16*)  alloc((size_t)768 * 256 * 2);
    u16*   wob  = (u16*)  alloc((size_t)256 * 256 * 2);
    u16*   w1b  = (u16*)  alloc((size_t)1024 * 256 * 2);
    u16*   w2b  = (u16*)  alloc((size_t)256 * 1024 * 2);
    float* bq   = (float*)alloc(768 * 4);

    convert_weights<<<3072, 256, 0, stream>>>(ipw, outw, w1, w2, ipb, wqkv, wob, w1b, w2b, bq);
    ln_kernel<<<2048, 256, 0, stream>>>(src, g1, be1, xf, xb);
    gemm_nt<0><<<dim3(128, 12), 256, 0, stream>>>(xb, wqkv, bq, nullptr, nullptr, qkv, 768, 256);
    transpose_v<<<dim3(16, 64), 256, 0, stream>>>(qkv, Vt);
    attn_kernel<<<dim3(16, 64), 256, 0, stream>>>(qkv, Vt, bias, ctx);
    oproj_ln<<<512, 64, 0, stream>>>(ctx, wob, outb, xf, g2, be2, yf, yb);
    gemm_nt<2><<<dim3(128, 16), 256, 0, stream>>>(yb, w1b, b1, nullptr, nullptr, hb, 1024, 256);
    gemm_nt<3><<<dim3(128, 4), 256, 0, stream>>>(hb, w2b, b2, yf, (float*)d_out, nullptr, 256, 1024);
}

// Round 4
// 201.427 us; speedup vs baseline: 1.2893x; 1.2893x over previous
//
#include <hip/hip_runtime.h>
#include <hip/hip_bf16.h>
#include <cstdint>

typedef unsigned short u16;
typedef __attribute__((ext_vector_type(8))) short bf16x8;
typedef __attribute__((ext_vector_type(4))) float f32x4;

#define S_LEN 1024
#define BATCH 8
#define DMODEL 256
#define NHEAD 8
#define HDIM 32
#define DFF 1024
#define NROWS (S_LEN * BATCH)   // 8192

static __device__ __forceinline__ u16 f2b(float f) {
    union { float f; unsigned u; } x{f};
    unsigned r = (x.u + 0x7fffu + ((x.u >> 16) & 1u)) >> 16;
    return (u16)r;
}

// ---------------------------------------------------------------------------
// Weight conversion (vectorized x4): f32 -> bf16, q-scale folded into Wq/bq.
// ---------------------------------------------------------------------------
__global__ __launch_bounds__(256) void convert_weights(
    const float* __restrict__ ipw, const float* __restrict__ outw,
    const float* __restrict__ w1, const float* __restrict__ w2,
    const float* __restrict__ ipb,
    u16* __restrict__ wqkv, u16* __restrict__ wout,
    u16* __restrict__ w1b, u16* __restrict__ w2b, float* __restrict__ bq)
{
    const float s = 0.17677669529663689f; // 1/sqrt(32)
    const int i4 = (blockIdx.x * 256 + threadIdx.x) * 4;
    const float* src; u16* dst; int off; float sc = 1.0f;
    if (i4 < 196608)      { src = ipw;  dst = wqkv; off = 0;      if (i4 < 65536) sc = s; }
    else if (i4 < 262144) { src = outw; dst = wout; off = 196608; }
    else if (i4 < 524288) { src = w1;   dst = w1b;  off = 262144; }
    else                  { src = w2;   dst = w2b;  off = 524288; }
    const float4 v = *(const float4*)(src + i4 - off);
    uint2 pk;
    pk.x = (unsigned)f2b(v.x * sc) | ((unsigned)f2b(v.y * sc) << 16);
    pk.y = (unsigned)f2b(v.z * sc) | ((unsigned)f2b(v.w * sc) << 16);
    *(uint2*)(dst + i4 - off) = pk;
    if (i4 < 768) {
        const float4 b = *(const float4*)(ipb + i4);
        const float bs = (i4 < 256) ? s : 1.0f;
        *(float4*)(bq + i4) = make_float4(b.x * bs, b.y * bs, b.z * bs, b.w * bs);
    }
}

// ---------------------------------------------------------------------------
// LayerNorm (LN1): one wave per row of 256; outputs f32 and bf16 copies.
// ---------------------------------------------------------------------------
__global__ __launch_bounds__(256) void ln_kernel(
    const float* __restrict__ in, const float* __restrict__ g,
    const float* __restrict__ be, float* __restrict__ of, u16* __restrict__ ob)
{
    const int w = threadIdx.x >> 6, l = threadIdx.x & 63;
    const int row = blockIdx.x * 4 + w;
    const float4 v = *(const float4*)(in + (size_t)row * DMODEL + l * 4);
    float s = v.x + v.y + v.z + v.w;
    #pragma unroll
    for (int o = 32; o; o >>= 1) s += __shfl_xor(s, o);
    const float mu = s * (1.0f / DMODEL);
    const float dx = v.x - mu, dy = v.y - mu, dz = v.z - mu, dw = v.w - mu;
    float sq = dx * dx + dy * dy + dz * dz + dw * dw;
    #pragma unroll
    for (int o = 32; o; o >>= 1) sq += __shfl_xor(sq, o);
    const float rs = rsqrtf(sq * (1.0f / DMODEL) + 1e-5f);
    const float4 gv = *(const float4*)(g + l * 4);
    const float4 bv = *(const float4*)(be + l * 4);
    const float r0 = dx * rs * gv.x + bv.x;
    const float r1 = dy * rs * gv.y + bv.y;
    const float r2 = dz * rs * gv.z + bv.z;
    const float r3 = dw * rs * gv.w + bv.w;
    *(float4*)(of + (size_t)row * DMODEL + l * 4) = make_float4(r0, r1, r2, r3);
    uint2 pk;
    pk.x = (unsigned)f2b(r0) | ((unsigned)f2b(r1) << 16);
    pk.y = (unsigned)f2b(r2) | ((unsigned)f2b(r3) << 16);
    *(uint2*)(ob + (size_t)row * DMODEL + l * 4) = pk;
}

// ---------------------------------------------------------------------------
// GEMM with LDS-staged B (shared across the 4 waves), direct-global A.
// C[M,N] = A[M,K] @ Bw[N,K]^T; transposed-accumulator mfma(B,A) epilogue.
// MODE 0: +bias -> bf16. MODE 2: +bias, relu -> bf16. MODE 3: +bias+resid -> f32.
// block 256 thr (4 waves x 16 rows), tile 64x64, BK=64; grid (M/64, N/64).
// ---------------------------------------------------------------------------
template <int MODE>
__global__ __launch_bounds__(256) void gemm_nt(
    const u16* __restrict__ A, const u16* __restrict__ Bw,
    const float* __restrict__ bias, const float* __restrict__ resid,
    float* __restrict__ outf, u16* __restrict__ outb,
    int N, int K)
{
    __shared__ u16 sB[64 * 64];
    const int tid = threadIdx.x, w = tid >> 6, l = tid & 63;
    const int g = l >> 4, q = l & 15;
    const int row = blockIdx.x * 64 + w * 16 + q;
    const int nbase = blockIdx.y * 64;
    f32x4 acc[4] = {{0,0,0,0},{0,0,0,0},{0,0,0,0},{0,0,0,0}};
    const u16* Arow = A + (size_t)row * K + g * 8;

    for (int kk = 0; kk < K; kk += 64) {
        __syncthreads();
        #pragma unroll
        for (int it = 0; it < 2; ++it) {
            const int idx = it * 256 + tid;
            const int br = idx >> 3, seg = idx & 7;
            const uint4 v = *(const uint4*)(Bw + (size_t)(nbase + br) * K + kk + seg * 8);
            *(uint4*)(&sB[(br * 128 + ((seg * 16) ^ ((br & 7) << 4))) >> 1]) = v;
        }
        __syncthreads();
        #pragma unroll
        for (int ks = 0; ks < 2; ++ks) {
            const bf16x8 af = *(const bf16x8*)(Arow + kk + ks * 32);
            #pragma unroll
            for (int n = 0; n < 4; ++n) {
                const int br = n * 16 + q;
                const bf16x8 bf = *(const bf16x8*)(
                    &sB[(br * 128 + ((ks * 64 + g * 16) ^ ((br & 7) << 4))) >> 1]);
                acc[n] = __builtin_amdgcn_mfma_f32_16x16x32_bf16(bf, af, acc[n], 0, 0, 0);
            }
        }
    }

    #pragma unroll
    for (int n = 0; n < 4; ++n) {
        const int col = nbase + n * 16 + g * 4;
        const float4 bv = *(const float4*)(bias + col);
        float v0 = acc[n][0] + bv.x, v1 = acc[n][1] + bv.y;
        float v2 = acc[n][2] + bv.z, v3 = acc[n][3] + bv.w;
        if (MODE == 0 || MODE == 2) {
            if (MODE == 2) {
                v0 = fmaxf(v0, 0.f); v1 = fmaxf(v1, 0.f);
                v2 = fmaxf(v2, 0.f); v3 = fmaxf(v3, 0.f);
            }
            uint2 pk;
            pk.x = (unsigned)f2b(v0) | ((unsigned)f2b(v1) << 16);
            pk.y = (unsigned)f2b(v2) | ((unsigned)f2b(v3) << 16);
            *(uint2*)(outb + (size_t)row * N + col) = pk;
        } else {
            const float4 rv = *(const float4*)(resid + (size_t)row * N + col);
            *(float4*)(outf + (size_t)row * N + col) =
                make_float4(v0 + rv.x, v1 + rv.y, v2 + rv.z, v3 + rv.w);
        }
    }
}

// ---------------------------------------------------------------------------
// V transpose: qkv cols [512,768) -> Vt [B*H, HD, S] bf16.
// ---------------------------------------------------------------------------
__global__ __launch_bounds__(256) void transpose_v(
    const u16* __restrict__ qkv, u16* __restrict__ Vt)
{
    __shared__ u16 sT[32][68];
    const int st = blockIdx.x, bh = blockIdx.y;
    const int b = bh >> 3, h = bh & 7;
    const int t = threadIdx.x;
    const int srow = t >> 2, seg = t & 3;
    uint4 v = *(const uint4*)(qkv +
        ((size_t)((st * 64 + srow) * 8 + b)) * 768 + 512 + h * 32 + seg * 8);
    const u16* pv = (const u16*)&v;
    #pragma unroll
    for (int e = 0; e < 8; ++e) sT[seg * 8 + e][srow] = pv[e];
    __syncthreads();
    const int d = t >> 3, chunk = t & 7;
    u16 o[8];
    #pragma unroll
    for (int e = 0; e < 8; ++e) o[e] = sT[d][chunk * 8 + e];
    *(uint4*)(Vt + ((size_t)bh * 32 + d) * S_LEN + st * 64 + chunk * 8) = *(uint4*)o;
}

// ---------------------------------------------------------------------------
// Flash attention: lane-local softmax (swapped operands), 2-deep software
// pipeline on the bias stream (nontemporal — read-once 268 MB).
// grid (S/64, B*H), 256 thr (4 independent waves x 16 q-rows).
// ---------------------------------------------------------------------------
__global__ __launch_bounds__(256) void attn_kernel(
    const u16* __restrict__ qkv, const u16* __restrict__ Vt,
    const float* __restrict__ bias, u16* __restrict__ ctx)
{
    __shared__ u16 sP[4][16 * 64];
    const int tid = threadIdx.x, w = tid >> 6, l = tid & 63;
    const int g = l >> 4, q = l & 15;
    const int bh = blockIdx.y, b = bh >> 3, h = bh & 7;
    const int qrow = blockIdx.x * 64 + w * 16 + q;

    const bf16x8 qf = *(const bf16x8*)(qkv + ((size_t)qrow * 8 + b) * 768 + h * 32 + g * 8);
    const u16* Kp = qkv + (size_t)b * 768 + 256 + h * 32 + g * 8;     // + krow*6144
    const u16* Vp = Vt + ((size_t)bh * 32 + q) * S_LEN + g * 8;       // + jg*16*1024
    const float* brow = bias + ((size_t)bh * S_LEN + qrow) * S_LEN;
    u16* Pw = sP[w];
    const int swz = (q & 7) << 4;

    f32x4 ctxa[2] = {{0,0,0,0},{0,0,0,0}};
    float m = -1e30f, lsum = 0.f;

    auto loadB = [&](int kt, f32x4* bv) {
        #pragma unroll
        for (int n = 0; n < 4; ++n)
            bv[n] = __builtin_nontemporal_load(
                (const f32x4*)(brow + kt * 64 + n * 16 + g * 4));
    };

    auto proc = [&](int kt, const f32x4* bv) {
        // K fragments + V fragments (L2/L3-resident; issued early in body)
        bf16x8 kf[4];
        #pragma unroll
        for (int n = 0; n < 4; ++n)
            kf[n] = *(const bf16x8*)(Kp + (size_t)(kt * 64 + n * 16 + q) * 6144);
        bf16x8 vf[2][2];
        #pragma unroll
        for (int ks = 0; ks < 2; ++ks)
            #pragma unroll
            for (int jg = 0; jg < 2; ++jg)
                vf[ks][jg] = *(const bf16x8*)(Vp + (size_t)jg * 16 * S_LEN + kt * 64 + ks * 32);

        f32x4 sc[4];
        #pragma unroll
        for (int n = 0; n < 4; ++n) {
            f32x4 z = {0, 0, 0, 0};
            sc[n] = __builtin_amdgcn_mfma_f32_16x16x32_bf16(kf[n], qf, z, 0, 0, 0);
        }
        #pragma unroll
        for (int n = 0; n < 4; ++n)
            #pragma unroll
            for (int r = 0; r < 4; ++r) sc[n][r] += bv[n][r];

        // online softmax, lane-local (row q); reduce across g via 2 shfl
        float mx = sc[0][0];
        #pragma unroll
        for (int n = 0; n < 4; ++n)
            #pragma unroll
            for (int r = 0; r < 4; ++r) mx = fmaxf(mx, sc[n][r]);
        mx = fmaxf(mx, __shfl_xor(mx, 16));
        mx = fmaxf(mx, __shfl_xor(mx, 32));
        const float mn = fmaxf(m, mx);
        const float corr = __expf(m - mn);
        float su = 0.f;
        u16 pb[16];
        #pragma unroll
        for (int n = 0; n < 4; ++n)
            #pragma unroll
            for (int r = 0; r < 4; ++r) {
                const float pv = __expf(sc[n][r] - mn);
                su += pv;
                pb[n * 4 + r] = f2b(pv);
            }
        su += __shfl_xor(su, 16);
        su += __shfl_xor(su, 32);
        lsum = lsum * corr + su;
        m = mn;
        #pragma unroll
        for (int jg = 0; jg < 2; ++jg)
            #pragma unroll
            for (int r = 0; r < 4; ++r) ctxa[jg][r] *= corr;

        // P -> per-wave LDS (packed b64, XOR-swizzled)
        #pragma unroll
        for (int n = 0; n < 4; ++n) {
            uint2 pk;
            pk.x = (unsigned)pb[n * 4] | ((unsigned)pb[n * 4 + 1] << 16);
            pk.y = (unsigned)pb[n * 4 + 2] | ((unsigned)pb[n * 4 + 3] << 16);
            *(uint2*)((char*)Pw + q * 128 + ((n * 32 + g * 8) ^ swz)) = pk;
        }

        // ctx^T += V^T x P
        #pragma unroll
        for (int ks = 0; ks < 2; ++ks) {
            const bf16x8 pf = *(const bf16x8*)((char*)Pw + q * 128 + ((ks * 64 + g * 16) ^ swz));
            #pragma unroll
            for (int jg = 0; jg < 2; ++jg)
                ctxa[jg] = __builtin_amdgcn_mfma_f32_16x16x32_bf16(vf[ks][jg], pf, ctxa[jg], 0, 0, 0);
        }
    };

    f32x4 bvA[4], bvB[4];
    loadB(0, bvA);
    for (int kt = 0; kt < 16; kt += 2) {
        loadB(kt + 1, bvB);
        proc(kt, bvA);
        if (kt + 2 < 16) loadB(kt + 2, bvA);
        proc(kt + 1, bvB);
    }

    const float inv = 1.0f / lsum;
    #pragma unroll
    for (int jg = 0; jg < 2; ++jg) {
        uint2 pk;
        pk.x = (unsigned)f2b(ctxa[jg][0] * inv) | ((unsigned)f2b(ctxa[jg][1] * inv) << 16);
        pk.y = (unsigned)f2b(ctxa[jg][2] * inv) | ((unsigned)f2b(ctxa[jg][3] * inv) << 16);
        *(uint2*)(ctx + ((size_t)qrow * 8 + b) * DMODEL + h * 32 + jg * 16 + g * 4) = pk;
    }
}

// ---------------------------------------------------------------------------
// Fused out-proj + residual(xf) + LayerNorm2 -> yf (f32), yb (bf16).
// 256-thr blocks: 4 waves share 16 rows, N split 4x64 (acc[4] each);
// cross-wave LN reduce via tiny LDS. grid = NROWS/16 = 512.
// ---------------------------------------------------------------------------
__global__ __launch_bounds__(256) void oproj_ln(
    const u16* __restrict__ ctx, const u16* __restrict__ wob,
    const float* __restrict__ ob, const float* __restrict__ xf,
    const float* __restrict__ g2, const float* __restrict__ be2,
    float* __restrict__ yf, u16* __restrict__ yb)
{
    __shared__ float s1[4][16], s2[4][16];
    const int tid = threadIdx.x, wv = tid >> 6, l = tid & 63;
    const int g = l >> 4, q = l & 15;
    const int row = blockIdx.x * 16 + q;
    f32x4 acc[4] = {{0,0,0,0},{0,0,0,0},{0,0,0,0},{0,0,0,0}};
    const u16* Arow = ctx + (size_t)row * 256 + g * 8;
    const u16* Brow = wob + (size_t)(wv * 64 + q) * 256 + g * 8;

    #pragma unroll 2
    for (int kk = 0; kk < 256; kk += 32) {
        const bf16x8 af = *(const bf16x8*)(Arow + kk);
        #pragma unroll
        for (int n = 0; n < 4; ++n) {
            const bf16x8 bf = *(const bf16x8*)(Brow + (size_t)n * 16 * 256 + kk);
            acc[n] = __builtin_amdgcn_mfma_f32_16x16x32_bf16(bf, af, acc[n], 0, 0, 0);
        }
    }

    float sum = 0.f;
    #pragma unroll
    for (int n = 0; n < 4; ++n) {
        const int col = wv * 64 + n * 16 + g * 4;
        const float4 bv = *(const float4*)(ob + col);
        const float4 rv = *(const float4*)(xf + (size_t)row * 256 + col);
        acc[n][0] += bv.x + rv.x; acc[n][1] += bv.y + rv.y;
        acc[n][2] += bv.z + rv.z; acc[n][3] += bv.w + rv.w;
        sum += acc[n][0] + acc[n][1] + acc[n][2] + acc[n][3];
    }
    sum += __shfl_xor(sum, 16);
    sum += __shfl_xor(sum, 32);
    if (l < 16) s1[wv][q] = sum;
    __syncthreads();
    const float mu = (s1[0][q] + s1[1][q] + s1[2][q] + s1[3][q]) * (1.0f / 256);
    float sq = 0.f;
    #pragma unroll
    for (int n = 0; n < 4; ++n)
        #pragma unroll
        for (int r = 0; r < 4; ++r) {
            const float d = acc[n][r] - mu;
            sq += d * d;
        }
    sq += __shfl_xor(sq, 16);
    sq += __shfl_xor(sq, 32);
    if (l < 16) s2[wv][q] = sq;
    __syncthreads();
    const float rs = rsqrtf((s2[0][q] + s2[1][q] + s2[2][q] + s2[3][q]) * (1.0f / 256) + 1e-5f);

    #pragma unroll
    for (int n = 0; n < 4; ++n) {
        const int col = wv * 64 + n * 16 + g * 4;
        const float4 gv = *(const float4*)(g2 + col);
        const float4 b2 = *(const float4*)(be2 + col);
        const float y0 = (acc[n][0] - mu) * rs * gv.x + b2.x;
        const float y1 = (acc[n][1] - mu) * rs * gv.y + b2.y;
        const float y2 = (acc[n][2] - mu) * rs * gv.z + b2.z;
        const float y3 = (acc[n][3] - mu) * rs * gv.w + b2.w;
        *(float4*)(yf + (size_t)row * 256 + col) = make_float4(y0, y1, y2, y3);
        uint2 pk;
        pk.x = (unsigned)f2b(y0) | ((unsigned)f2b(y1) << 16);
        pk.y = (unsigned)f2b(y2) | ((unsigned)f2b(y3) << 16);
        *(uint2*)(yb + (size_t)row * 256 + col) = pk;
    }
}

// ---------------------------------------------------------------------------
extern "C" void kernel_launch(void* const* d_in, const int* in_sizes, int n_in,
                              void* d_out, int out_size, void* d_ws, size_t ws_size,
                              hipStream_t stream)
{
    const float* src  = (const float*)d_in[0];
    const float* bias = (const float*)d_in[1];
    const float* ipw  = (const float*)d_in[2];
    const float* ipb  = (const float*)d_in[3];
    const float* outw = (const float*)d_in[4];
    const float* outb = (const float*)d_in[5];
    const float* w1   = (const float*)d_in[6];
    const float* b1   = (const float*)d_in[7];
    const float* w2   = (const float*)d_in[8];
    const float* b2   = (const float*)d_in[9];
    const float* g1   = (const float*)d_in[10];
    const float* be1  = (const float*)d_in[11];
    const float* g2   = (const float*)d_in[12];
    const float* be2  = (const float*)d_in[13];

    char* p = (char*)d_ws;
    auto alloc = [&](size_t bytes) -> void* {
        void* r = (void*)p;
        p += (bytes + 255) & ~(size_t)255;
        return r;
    };
    float* xf   = (float*)alloc((size_t)NROWS * DMODEL * 4);
    u16*   xb   = (u16*)  alloc((size_t)NROWS * DMODEL * 2);
    u16*   qkv  = (u16*)  alloc((size_t)NROWS * 768 * 2);
    u16*   Vt   = (u16*)  alloc((size_t)64 * S_LEN * HDIM * 2);
    u16*   ctx  = (u16*)  alloc((size_t)NROWS * DMODEL * 2);
    float* yf   = (float*)alloc((size_t)NROWS * DMODEL * 4);
    u16*   yb   = (u16*)  alloc((size_t)NROWS * DMODEL * 2);
    u16*   hb   = (u16*)  alloc((size_t)NROWS * DFF * 2);
    u16*   wqkv = (u16*)  alloc((size_t)768 * 256 * 2);
    u16*   wob  = (u16*)  alloc((size_t)256 * 256 * 2);
    u16*   w1b  = (u16*)  alloc((size_t)1024 * 256 * 2);
    u16*   w2b  = (u16*)  alloc((size_t)256 * 1024 * 2);
    float* bq   = (float*)alloc(768 * 4);

    convert_weights<<<768, 256, 0, stream>>>(ipw, outw, w1, w2, ipb, wqkv, wob, w1b, w2b, bq);
    ln_kernel<<<2048, 256, 0, stream>>>(src, g1, be1, xf, xb);
    gemm_nt<0><<<dim3(128, 12), 256, 0, stream>>>(xb, wqkv, bq, nullptr, nullptr, qkv, 768, 256);
    transpose_v<<<dim3(16, 64), 256, 0, stream>>>(qkv, Vt);
    attn_kernel<<<dim3(16, 64), 256, 0, stream>>>(qkv, Vt, bias, ctx);
    oproj_ln<<<512, 256, 0, stream>>>(ctx, wob, outb, xf, g2, be2, yf, yb);
    gemm_nt<2><<<dim3(128, 16), 256, 0, stream>>>(yb, w1b, b1, nullptr, nullptr, hb, 1024, 256);
    gemm_nt<3><<<dim3(128, 4), 256, 0, stream>>>(hb, w2b, b2, yf, (float*)d_out, nullptr, 256, 1024);
}

// Round 5
// 169.715 us; speedup vs baseline: 1.5302x; 1.1869x over previous
//
#include <hip/hip_runtime.h>
#include <hip/hip_bf16.h>
#include <cstdint>

typedef unsigned short u16;
typedef __attribute__((ext_vector_type(8))) short bf16x8;
typedef __attribute__((ext_vector_type(4))) float f32x4;

#define S_LEN 1024
#define BATCH 8
#define DMODEL 256
#define NHEAD 8
#define HDIM 32
#define DFF 1024
#define NROWS (S_LEN * BATCH)   // 8192

static __device__ __forceinline__ u16 f2b(float f) {
    union { float f; unsigned u; } x{f};
    unsigned r = (x.u + 0x7fffu + ((x.u >> 16) & 1u)) >> 16;
    return (u16)r;
}

// ---------------------------------------------------------------------------
// Weight conversion (vectorized x4): f32 -> bf16, q-scale folded into Wq/bq.
// ---------------------------------------------------------------------------
__global__ __launch_bounds__(256) void convert_weights(
    const float* __restrict__ ipw, const float* __restrict__ outw,
    const float* __restrict__ w1, const float* __restrict__ w2,
    const float* __restrict__ ipb,
    u16* __restrict__ wqkv, u16* __restrict__ wout,
    u16* __restrict__ w1b, u16* __restrict__ w2b, float* __restrict__ bq)
{
    const float s = 0.17677669529663689f; // 1/sqrt(32)
    const int i4 = (blockIdx.x * 256 + threadIdx.x) * 4;
    const float* src; u16* dst; int off; float sc = 1.0f;
    if (i4 < 196608)      { src = ipw;  dst = wqkv; off = 0;      if (i4 < 65536) sc = s; }
    else if (i4 < 262144) { src = outw; dst = wout; off = 196608; }
    else if (i4 < 524288) { src = w1;   dst = w1b;  off = 262144; }
    else                  { src = w2;   dst = w2b;  off = 524288; }
    const float4 v = *(const float4*)(src + i4 - off);
    uint2 pk;
    pk.x = (unsigned)f2b(v.x * sc) | ((unsigned)f2b(v.y * sc) << 16);
    pk.y = (unsigned)f2b(v.z * sc) | ((unsigned)f2b(v.w * sc) << 16);
    *(uint2*)(dst + i4 - off) = pk;
    if (i4 < 768) {
        const float4 b = *(const float4*)(ipb + i4);
        const float bs = (i4 < 256) ? s : 1.0f;
        *(float4*)(bq + i4) = make_float4(b.x * bs, b.y * bs, b.z * bs, b.w * bs);
    }
}

// ---------------------------------------------------------------------------
// LayerNorm (LN1): one wave per row of 256; outputs f32 and bf16 copies.
// ---------------------------------------------------------------------------
__global__ __launch_bounds__(256) void ln_kernel(
    const float* __restrict__ in, const float* __restrict__ g,
    const float* __restrict__ be, float* __restrict__ of, u16* __restrict__ ob)
{
    const int w = threadIdx.x >> 6, l = threadIdx.x & 63;
    const int row = blockIdx.x * 4 + w;
    const float4 v = *(const float4*)(in + (size_t)row * DMODEL + l * 4);
    float s = v.x + v.y + v.z + v.w;
    #pragma unroll
    for (int o = 32; o; o >>= 1) s += __shfl_xor(s, o);
    const float mu = s * (1.0f / DMODEL);
    const float dx = v.x - mu, dy = v.y - mu, dz = v.z - mu, dw = v.w - mu;
    float sq = dx * dx + dy * dy + dz * dz + dw * dw;
    #pragma unroll
    for (int o = 32; o; o >>= 1) sq += __shfl_xor(sq, o);
    const float rs = rsqrtf(sq * (1.0f / DMODEL) + 1e-5f);
    const float4 gv = *(const float4*)(g + l * 4);
    const float4 bv = *(const float4*)(be + l * 4);
    const float r0 = dx * rs * gv.x + bv.x;
    const float r1 = dy * rs * gv.y + bv.y;
    const float r2 = dz * rs * gv.z + bv.z;
    const float r3 = dw * rs * gv.w + bv.w;
    *(float4*)(of + (size_t)row * DMODEL + l * 4) = make_float4(r0, r1, r2, r3);
    uint2 pk;
    pk.x = (unsigned)f2b(r0) | ((unsigned)f2b(r1) << 16);
    pk.y = (unsigned)f2b(r2) | ((unsigned)f2b(r3) << 16);
    *(uint2*)(ob + (size_t)row * DMODEL + l * 4) = pk;
}

// ---------------------------------------------------------------------------
// QKV GEMM with head-contiguous epilogue: writes Qh/Kh [BH,S,32] (uint2) and
// Vt [BH,32,S] (16-lane-contiguous u16 stores). LDS-staged B, direct A.
// block 256 thr, tile 64x64, grid (128, 12). Kills reshape/transpose kernels.
// ---------------------------------------------------------------------------
__global__ __launch_bounds__(256) void gemm_qkv(
    const u16* __restrict__ A, const u16* __restrict__ Bw,
    const float* __restrict__ bias,
    u16* __restrict__ Qh, u16* __restrict__ Kh, u16* __restrict__ Vt)
{
    __shared__ u16 sB[64 * 64];
    const int K = 256;
    const int tid = threadIdx.x, w = tid >> 6, l = tid & 63;
    const int g = l >> 4, q = l & 15;
    const int row = blockIdx.x * 64 + w * 16 + q;
    const int nbase = blockIdx.y * 64;
    f32x4 acc[4] = {{0,0,0,0},{0,0,0,0},{0,0,0,0},{0,0,0,0}};
    const u16* Arow = A + (size_t)row * K + g * 8;

    for (int kk = 0; kk < K; kk += 64) {
        __syncthreads();
        #pragma unroll
        for (int it = 0; it < 2; ++it) {
            const int idx = it * 256 + tid;
            const int br = idx >> 3, seg = idx & 7;
            const uint4 v = *(const uint4*)(Bw + (size_t)(nbase + br) * K + kk + seg * 8);
            *(uint4*)(&sB[(br * 128 + ((seg * 16) ^ ((br & 7) << 4))) >> 1]) = v;
        }
        __syncthreads();
        #pragma unroll
        for (int ks = 0; ks < 2; ++ks) {
            const bf16x8 af = *(const bf16x8*)(Arow + kk + ks * 32);
            #pragma unroll
            for (int n = 0; n < 4; ++n) {
                const int br = n * 16 + q;
                const bf16x8 bf = *(const bf16x8*)(
                    &sB[(br * 128 + ((ks * 64 + g * 16) ^ ((br & 7) << 4))) >> 1]);
                acc[n] = __builtin_amdgcn_mfma_f32_16x16x32_bf16(bf, af, acc[n], 0, 0, 0);
            }
        }
    }

    const int s = row >> 3, b = row & 7;
    if (nbase < 512) {
        u16* dst = (nbase >= 256) ? Kh : Qh;
        #pragma unroll
        for (int n = 0; n < 4; ++n) {
            const int col = nbase + n * 16 + g * 4;
            const float4 bv = *(const float4*)(bias + col);
            const int cc = col & 255, h = cc >> 5, hd = cc & 31;
            const int bh = b * 8 + h;
            uint2 pk;
            pk.x = (unsigned)f2b(acc[n][0] + bv.x) | ((unsigned)f2b(acc[n][1] + bv.y) << 16);
            pk.y = (unsigned)f2b(acc[n][2] + bv.z) | ((unsigned)f2b(acc[n][3] + bv.w) << 16);
            *(uint2*)(dst + ((size_t)bh * S_LEN + s) * HDIM + hd) = pk;
        }
    } else {
        #pragma unroll
        for (int n = 0; n < 4; ++n) {
            const int col = nbase + n * 16 + g * 4;
            const float4 bv = *(const float4*)(bias + col);
            const int cc = col - 512, h = cc >> 5, hd = cc & 31;
            const int bh = b * 8 + h;
            Vt[((size_t)bh * HDIM + hd + 0) * S_LEN + s] = f2b(acc[n][0] + bv.x);
            Vt[((size_t)bh * HDIM + hd + 1) * S_LEN + s] = f2b(acc[n][1] + bv.y);
            Vt[((size_t)bh * HDIM + hd + 2) * S_LEN + s] = f2b(acc[n][2] + bv.z);
            Vt[((size_t)bh * HDIM + hd + 3) * S_LEN + s] = f2b(acc[n][3] + bv.w);
        }
    }
}

// ---------------------------------------------------------------------------
// Flash attention: LDS-staged K/V in MFMA-fragment order (conflict-free b128,
// double-buffered, T14 async-split), lane-local softmax, pipelined
// nontemporal bias stream. grid (S/64, B*H), 256 thr (4 waves x 16 q-rows).
// ---------------------------------------------------------------------------
__global__ __launch_bounds__(256) void attn_kernel(
    const u16* __restrict__ Qh, const u16* __restrict__ Kh,
    const u16* __restrict__ Vt, const float* __restrict__ bias,
    u16* __restrict__ ctx)
{
    __shared__ u16 sK[2][64 * 32];   // slot (n*64+l): K[n*16+(l&15)][(l>>4)*8 ..]
    __shared__ u16 sV[2][32 * 64];   // slot (c*64+l): V^T[(c&1)*16+(l&15)][(c>>1)*32+(l>>4)*8 ..]
    __shared__ u16 sP[4][16 * 64];
    const int tid = threadIdx.x, w = tid >> 6, l = tid & 63;
    const int g = l >> 4, q = l & 15;
    const int bh = blockIdx.y, b = bh >> 3, h = bh & 7;
    const int qbase = blockIdx.x * 64 + w * 16;
    const int qrow = qbase + q;

    const bf16x8 qf = *(const bf16x8*)(Qh + ((size_t)bh * S_LEN + qrow) * HDIM + g * 8);
    const float* brow = bias + ((size_t)bh * S_LEN + qrow) * S_LEN;
    u16* Pw = sP[w];
    const int swz = (q & 7) << 4;

    // per-thread staging addresses (wave w owns fragment slot w)
    const u16* KsrcBase = Kh + ((size_t)bh * S_LEN + w * 16 + q) * HDIM + g * 8;          // + kt*64*32
    const u16* VsrcBase = Vt + ((size_t)bh * HDIM + (w & 1) * 16 + q) * S_LEN
                             + (w >> 1) * 32 + g * 8;                                      // + kt*64
    u16* KdstA = &sK[0][tid * 8]; u16* KdstB = &sK[1][tid * 8];
    u16* VdstA = &sV[0][tid * 8]; u16* VdstB = &sV[1][tid * 8];

    f32x4 ctxa[2] = {{0,0,0,0},{0,0,0,0}};
    float m = -1e30f, lsum = 0.f;

    auto loadB = [&](int kt, f32x4* bv) {
        #pragma unroll
        for (int n = 0; n < 4; ++n)
            bv[n] = __builtin_nontemporal_load(
                (const f32x4*)(brow + kt * 64 + n * 16 + g * 4));
    };

    auto proc = [&](int buf, const f32x4* bv) {
        f32x4 sc[4];
        #pragma unroll
        for (int n = 0; n < 4; ++n) {
            const bf16x8 kf = *(const bf16x8*)(&sK[buf][(n * 64 + l) * 8]);
            f32x4 z = {0, 0, 0, 0};
            sc[n] = __builtin_amdgcn_mfma_f32_16x16x32_bf16(kf, qf, z, 0, 0, 0);
        }
        #pragma unroll
        for (int n = 0; n < 4; ++n)
            #pragma unroll
            for (int r = 0; r < 4; ++r) sc[n][r] += bv[n][r];

        // online softmax, lane-local (row q); reduce across g via 2 shfl
        float mx = sc[0][0];
        #pragma unroll
        for (int n = 0; n < 4; ++n)
            #pragma unroll
            for (int r = 0; r < 4; ++r) mx = fmaxf(mx, sc[n][r]);
        mx = fmaxf(mx, __shfl_xor(mx, 16));
        mx = fmaxf(mx, __shfl_xor(mx, 32));
        const float mn = fmaxf(m, mx);
        const float corr = __expf(m - mn);
        float su = 0.f;
        u16 pb[16];
        #pragma unroll
        for (int n = 0; n < 4; ++n)
            #pragma unroll
            for (int r = 0; r < 4; ++r) {
                const float pv = __expf(sc[n][r] - mn);
                su += pv;
                pb[n * 4 + r] = f2b(pv);
            }
        su += __shfl_xor(su, 16);
        su += __shfl_xor(su, 32);
        lsum = lsum * corr + su;
        m = mn;
        #pragma unroll
        for (int jg = 0; jg < 2; ++jg)
            #pragma unroll
            for (int r = 0; r < 4; ++r) ctxa[jg][r] *= corr;

        // P -> per-wave LDS (packed b64, XOR-swizzled)
        #pragma unroll
        for (int n = 0; n < 4; ++n) {
            uint2 pk;
            pk.x = (unsigned)pb[n * 4] | ((unsigned)pb[n * 4 + 1] << 16);
            pk.y = (unsigned)pb[n * 4 + 2] | ((unsigned)pb[n * 4 + 3] << 16);
            *(uint2*)((char*)Pw + q * 128 + ((n * 32 + g * 8) ^ swz)) = pk;
        }

        // ctx^T += V^T x P  (fragments from LDS, conflict-free linear slots)
        #pragma unroll
        for (int ks = 0; ks < 2; ++ks) {
            const bf16x8 pf = *(const bf16x8*)((char*)Pw + q * 128 + ((ks * 64 + g * 16) ^ swz));
            #pragma unroll
            for (int jg = 0; jg < 2; ++jg) {
                const bf16x8 vf = *(const bf16x8*)(&sV[buf][((ks * 2 + jg) * 64 + l) * 8]);
                ctxa[jg] = __builtin_amdgcn_mfma_f32_16x16x32_bf16(vf, pf, ctxa[jg], 0, 0, 0);
            }
        }
    };

    // prologue: stage tile 0 into buf0, load bias tile 0
    f32x4 bv0[4], bv1[4];
    {
        const uint4 kr = *(const uint4*)(KsrcBase);
        const uint4 vr = *(const uint4*)(VsrcBase);
        *(uint4*)KdstA = kr;
        *(uint4*)VdstA = vr;
        loadB(0, bv0);
    }
    __syncthreads();

    for (int kt = 0; kt < 16; kt += 2) {
        // even phase: compute buf0 (tile kt), stage tile kt+1 -> buf1
        {
            uint4 kr, vr;
            kr = *(const uint4*)(KsrcBase + (size_t)(kt + 1) * 64 * HDIM);
            vr = *(const uint4*)(VsrcBase + (size_t)(kt + 1) * 64);
            loadB(kt + 1, bv1);
            proc(0, bv0);
            *(uint4*)KdstB = kr;
            *(uint4*)VdstB = vr;
        }
        __syncthreads();
        // odd phase: compute buf1 (tile kt+1), stage tile kt+2 -> buf0
        {
            uint4 kr, vr;
            if (kt + 2 < 16) {
                kr = *(const uint4*)(KsrcBase + (size_t)(kt + 2) * 64 * HDIM);
                vr = *(const uint4*)(VsrcBase + (size_t)(kt + 2) * 64);
                loadB(kt + 2, bv0);
            }
            proc(1, bv1);
            if (kt + 2 < 16) {
                *(uint4*)KdstA = kr;
                *(uint4*)VdstA = vr;
            }
        }
        __syncthreads();
    }

    const float inv = 1.0f / lsum;
    #pragma unroll
    for (int jg = 0; jg < 2; ++jg) {
        uint2 pk;
        pk.x = (unsigned)f2b(ctxa[jg][0] * inv) | ((unsigned)f2b(ctxa[jg][1] * inv) << 16);
        pk.y = (unsigned)f2b(ctxa[jg][2] * inv) | ((unsigned)f2b(ctxa[jg][3] * inv) << 16);
        *(uint2*)(ctx + ((size_t)qrow * 8 + b) * DMODEL + h * 32 + jg * 16 + g * 4) = pk;
    }
}

// ---------------------------------------------------------------------------
// GEMM with LDS-staged B, direct-global A (FFN1 relu->bf16, FFN2 +resid->f32).
// ---------------------------------------------------------------------------
template <int MODE>   // 2: relu->bf16, 3: +resid->f32
__global__ __launch_bounds__(256) void gemm_nt(
    const u16* __restrict__ A, const u16* __restrict__ Bw,
    const float* __restrict__ bias, const float* __restrict__ resid,
    float* __restrict__ outf, u16* __restrict__ outb,
    int N, int K)
{
    __shared__ u16 sB[64 * 64];
    const int tid = threadIdx.x, w = tid >> 6, l = tid & 63;
    const int g = l >> 4, q = l & 15;
    const int row = blockIdx.x * 64 + w * 16 + q;
    const int nbase = blockIdx.y * 64;
    f32x4 acc[4] = {{0,0,0,0},{0,0,0,0},{0,0,0,0},{0,0,0,0}};
    const u16* Arow = A + (size_t)row * K + g * 8;

    for (int kk = 0; kk < K; kk += 64) {
        __syncthreads();
        #pragma unroll
        for (int it = 0; it < 2; ++it) {
            const int idx = it * 256 + tid;
            const int br = idx >> 3, seg = idx & 7;
            const uint4 v = *(const uint4*)(Bw + (size_t)(nbase + br) * K + kk + seg * 8);
            *(uint4*)(&sB[(br * 128 + ((seg * 16) ^ ((br & 7) << 4))) >> 1]) = v;
        }
        __syncthreads();
        #pragma unroll
        for (int ks = 0; ks < 2; ++ks) {
            const bf16x8 af = *(const bf16x8*)(Arow + kk + ks * 32);
            #pragma unroll
            for (int n = 0; n < 4; ++n) {
                const int br = n * 16 + q;
                const bf16x8 bf = *(const bf16x8*)(
                    &sB[(br * 128 + ((ks * 64 + g * 16) ^ ((br & 7) << 4))) >> 1]);
                acc[n] = __builtin_amdgcn_mfma_f32_16x16x32_bf16(bf, af, acc[n], 0, 0, 0);
            }
        }
    }

    #pragma unroll
    for (int n = 0; n < 4; ++n) {
        const int col = nbase + n * 16 + g * 4;
        const float4 bv = *(const float4*)(bias + col);
        float v0 = acc[n][0] + bv.x, v1 = acc[n][1] + bv.y;
        float v2 = acc[n][2] + bv.z, v3 = acc[n][3] + bv.w;
        if (MODE == 2) {
            v0 = fmaxf(v0, 0.f); v1 = fmaxf(v1, 0.f);
            v2 = fmaxf(v2, 0.f); v3 = fmaxf(v3, 0.f);
            uint2 pk;
            pk.x = (unsigned)f2b(v0) | ((unsigned)f2b(v1) << 16);
            pk.y = (unsigned)f2b(v2) | ((unsigned)f2b(v3) << 16);
            *(uint2*)(outb + (size_t)row * N + col) = pk;
        } else {
            const float4 rv = *(const float4*)(resid + (size_t)row * N + col);
            *(float4*)(outf + (size_t)row * N + col) =
                make_float4(v0 + rv.x, v1 + rv.y, v2 + rv.z, v3 + rv.w);
        }
    }
}

// ---------------------------------------------------------------------------
// Fused out-proj + residual(xf) + LayerNorm2 -> yf (f32), yb (bf16).
// ---------------------------------------------------------------------------
__global__ __launch_bounds__(256) void oproj_ln(
    const u16* __restrict__ ctx, const u16* __restrict__ wob,
    const float* __restrict__ ob, const float* __restrict__ xf,
    const float* __restrict__ g2, const float* __restrict__ be2,
    float* __restrict__ yf, u16* __restrict__ yb)
{
    __shared__ float s1[4][16], s2[4][16];
    const int tid = threadIdx.x, wv = tid >> 6, l = tid & 63;
    const int g = l >> 4, q = l & 15;
    const int row = blockIdx.x * 16 + q;
    f32x4 acc[4] = {{0,0,0,0},{0,0,0,0},{0,0,0,0},{0,0,0,0}};
    const u16* Arow = ctx + (size_t)row * 256 + g * 8;
    const u16* Brow = wob + (size_t)(wv * 64 + q) * 256 + g * 8;

    #pragma unroll 2
    for (int kk = 0; kk < 256; kk += 32) {
        const bf16x8 af = *(const bf16x8*)(Arow + kk);
        #pragma unroll
        for (int n = 0; n < 4; ++n) {
            const bf16x8 bf = *(const bf16x8*)(Brow + (size_t)n * 16 * 256 + kk);
            acc[n] = __builtin_amdgcn_mfma_f32_16x16x32_bf16(bf, af, acc[n], 0, 0, 0);
        }
    }

    float sum = 0.f;
    #pragma unroll
    for (int n = 0; n < 4; ++n) {
        const int col = wv * 64 + n * 16 + g * 4;
        const float4 bv = *(const float4*)(ob + col);
        const float4 rv = *(const float4*)(xf + (size_t)row * 256 + col);
        acc[n][0] += bv.x + rv.x; acc[n][1] += bv.y + rv.y;
        acc[n][2] += bv.z + rv.z; acc[n][3] += bv.w + rv.w;
        sum += acc[n][0] + acc[n][1] + acc[n][2] + acc[n][3];
    }
    sum += __shfl_xor(sum, 16);
    sum += __shfl_xor(sum, 32);
    if (l < 16) s1[wv][q] = sum;
    __syncthreads();
    const float mu = (s1[0][q] + s1[1][q] + s1[2][q] + s1[3][q]) * (1.0f / 256);
    float sq = 0.f;
    #pragma unroll
    for (int n = 0; n < 4; ++n)
        #pragma unroll
        for (int r = 0; r < 4; ++r) {
            const float d = acc[n][r] - mu;
            sq += d * d;
        }
    sq += __shfl_xor(sq, 16);
    sq += __shfl_xor(sq, 32);
    if (l < 16) s2[wv][q] = sq;
    __syncthreads();
    const float rs = rsqrtf((s2[0][q] + s2[1][q] + s2[2][q] + s2[3][q]) * (1.0f / 256) + 1e-5f);

    #pragma unroll
    for (int n = 0; n < 4; ++n) {
        const int col = wv * 64 + n * 16 + g * 4;
        const float4 gv = *(const float4*)(g2 + col);
        const float4 b2 = *(const float4*)(be2 + col);
        const float y0 = (acc[n][0] - mu) * rs * gv.x + b2.x;
        const float y1 = (acc[n][1] - mu) * rs * gv.y + b2.y;
        const float y2 = (acc[n][2] - mu) * rs * gv.z + b2.z;
        const float y3 = (acc[n][3] - mu) * rs * gv.w + b2.w;
        *(float4*)(yf + (size_t)row * 256 + col) = make_float4(y0, y1, y2, y3);
        uint2 pk;
        pk.x = (unsigned)f2b(y0) | ((unsigned)f2b(y1) << 16);
        pk.y = (unsigned)f2b(y2) | ((unsigned)f2b(y3) << 16);
        *(uint2*)(yb + (size_t)row * 256 + col) = pk;
    }
}

// ---------------------------------------------------------------------------
extern "C" void kernel_launch(void* const* d_in, const int* in_sizes, int n_in,
                              void* d_out, int out_size, void* d_ws, size_t ws_size,
                              hipStream_t stream)
{
    const float* src  = (const float*)d_in[0];
    const float* bias = (const float*)d_in[1];
    const float* ipw  = (const float*)d_in[2];
    const float* ipb  = (const float*)d_in[3];
    const float* outw = (const float*)d_in[4];
    const float* outb = (const float*)d_in[5];
    const float* w1   = (const float*)d_in[6];
    const float* b1   = (const float*)d_in[7];
    const float* w2   = (const float*)d_in[8];
    const float* b2   = (const float*)d_in[9];
    const float* g1   = (const float*)d_in[10];
    const float* be1  = (const float*)d_in[11];
    const float* g2   = (const float*)d_in[12];
    const float* be2  = (const float*)d_in[13];

    char* p = (char*)d_ws;
    auto alloc = [&](size_t bytes) -> void* {
        void* r = (void*)p;
        p += (bytes + 255) & ~(size_t)255;
        return r;
    };
    float* xf   = (float*)alloc((size_t)NROWS * DMODEL * 4);
    u16*   xb   = (u16*)  alloc((size_t)NROWS * DMODEL * 2);
    u16*   Qh   = (u16*)  alloc((size_t)64 * S_LEN * HDIM * 2);
    u16*   Kb   = (u16*)  alloc((size_t)64 * S_LEN * HDIM * 2);
    u16*   Vt   = (u16*)  alloc((size_t)64 * S_LEN * HDIM * 2);
    u16*   ctx  = (u16*)  alloc((size_t)NROWS * DMODEL * 2);
    float* yf   = (float*)alloc((size_t)NROWS * DMODEL * 4);
    u16*   yb   = (u16*)  alloc((size_t)NROWS * DMODEL * 2);
    u16*   hb   = (u16*)  alloc((size_t)NROWS * DFF * 2);
    u16*   wqkv = (u16*)  alloc((size_t)768 * 256 * 2);
    u16*   wob  = (u16*)  alloc((size_t)256 * 256 * 2);
    u16*   w1b  = (u16*)  alloc((size_t)1024 * 256 * 2);
    u16*   w2b  = (u16*)  alloc((size_t)256 * 1024 * 2);
    float* bq   = (float*)alloc(768 * 4);

    convert_weights<<<768, 256, 0, stream>>>(ipw, outw, w1, w2, ipb, wqkv, wob, w1b, w2b, bq);
    ln_kernel<<<2048, 256, 0, stream>>>(src, g1, be1, xf, xb);
    gemm_qkv<<<dim3(128, 12), 256, 0, stream>>>(xb, wqkv, bq, Qh, Kb, Vt);
    attn_kernel<<<dim3(16, 64), 256, 0, stream>>>(Qh, Kb, Vt, bias, ctx);
    oproj_ln<<<512, 256, 0, stream>>>(ctx, wob, outb, xf, g2, be2, yf, yb);
    gemm_nt<2><<<dim3(128, 16), 256, 0, stream>>>(yb, w1b, b1, nullptr, nullptr, hb, 1024, 256);
    gemm_nt<3><<<dim3(128, 4), 256, 0, stream>>>(hb, w2b, b2, yf, (float*)d_out, nullptr, 256, 1024);
}

// Round 6
// 157.333 us; speedup vs baseline: 1.6507x; 1.0787x over previous
//
#include <hip/hip_runtime.h>
#include <hip/hip_bf16.h>
#include <cstdint>

typedef unsigned short u16;
typedef __attribute__((ext_vector_type(8))) short bf16x8;
typedef __attribute__((ext_vector_type(4))) float f32x4;

#define S_LEN 1024
#define BATCH 8
#define DMODEL 256
#define NHEAD 8
#define HDIM 32
#define DFF 1024
#define NROWS (S_LEN * BATCH)   // 8192

static __device__ __forceinline__ u16 f2b(float f) {
    union { float f; unsigned u; } x{f};
    unsigned r = (x.u + 0x7fffu + ((x.u >> 16) & 1u)) >> 16;
    return (u16)r;
}

// ---------------------------------------------------------------------------
// Fused prep: blocks [0,2048) = LayerNorm1 (4 rows/block);
//             blocks [2048,2816) = weight f32->bf16 convert (q-scale folded).
// ---------------------------------------------------------------------------
__global__ __launch_bounds__(256) void prep_kernel(
    const float* __restrict__ in, const float* __restrict__ g1,
    const float* __restrict__ be1, float* __restrict__ of, u16* __restrict__ ob,
    const float* __restrict__ ipw, const float* __restrict__ outw,
    const float* __restrict__ w1, const float* __restrict__ w2,
    const float* __restrict__ ipb,
    u16* __restrict__ wqkv, u16* __restrict__ wout,
    u16* __restrict__ w1b, u16* __restrict__ w2b, float* __restrict__ bq)
{
    const float s = 0.17677669529663689f; // 1/sqrt(32)
    if (blockIdx.x >= 2048) {
        const int i4 = ((int)blockIdx.x - 2048) * 1024 + threadIdx.x * 4;
        const float* src; u16* dst; int off; float sc = 1.0f;
        if (i4 < 196608)      { src = ipw;  dst = wqkv; off = 0;      if (i4 < 65536) sc = s; }
        else if (i4 < 262144) { src = outw; dst = wout; off = 196608; }
        else if (i4 < 524288) { src = w1;   dst = w1b;  off = 262144; }
        else                  { src = w2;   dst = w2b;  off = 524288; }
        const float4 v = *(const float4*)(src + i4 - off);
        uint2 pk;
        pk.x = (unsigned)f2b(v.x * sc) | ((unsigned)f2b(v.y * sc) << 16);
        pk.y = (unsigned)f2b(v.z * sc) | ((unsigned)f2b(v.w * sc) << 16);
        *(uint2*)(dst + i4 - off) = pk;
        if (i4 < 768) {
            const float4 b = *(const float4*)(ipb + i4);
            const float bs = (i4 < 256) ? s : 1.0f;
            *(float4*)(bq + i4) = make_float4(b.x * bs, b.y * bs, b.z * bs, b.w * bs);
        }
        return;
    }
    const int w = threadIdx.x >> 6, l = threadIdx.x & 63;
    const int row = blockIdx.x * 4 + w;
    const float4 v = *(const float4*)(in + (size_t)row * DMODEL + l * 4);
    float s0 = v.x + v.y + v.z + v.w;
    #pragma unroll
    for (int o = 32; o; o >>= 1) s0 += __shfl_xor(s0, o);
    const float mu = s0 * (1.0f / DMODEL);
    const float dx = v.x - mu, dy = v.y - mu, dz = v.z - mu, dw = v.w - mu;
    float sq = dx * dx + dy * dy + dz * dz + dw * dw;
    #pragma unroll
    for (int o = 32; o; o >>= 1) sq += __shfl_xor(sq, o);
    const float rs = rsqrtf(sq * (1.0f / DMODEL) + 1e-5f);
    const float4 gv = *(const float4*)(g1 + l * 4);
    const float4 bv = *(const float4*)(be1 + l * 4);
    const float r0 = dx * rs * gv.x + bv.x;
    const float r1 = dy * rs * gv.y + bv.y;
    const float r2 = dz * rs * gv.z + bv.z;
    const float r3 = dw * rs * gv.w + bv.w;
    *(float4*)(of + (size_t)row * DMODEL + l * 4) = make_float4(r0, r1, r2, r3);
    uint2 pk;
    pk.x = (unsigned)f2b(r0) | ((unsigned)f2b(r1) << 16);
    pk.y = (unsigned)f2b(r2) | ((unsigned)f2b(r3) << 16);
    *(uint2*)(ob + (size_t)row * DMODEL + l * 4) = pk;
}

// ---------------------------------------------------------------------------
// Shared GEMM core: tile MF*64 (M) x 64 (N), BK=64 chunks, double-buffered
// LDS B with register prefetch (1 barrier per chunk). mfma(B,A) transposed
// accumulator: lane q = output row, g*4+r = output col within n-fragment.
// ---------------------------------------------------------------------------
template <int MF>
__device__ __forceinline__ void gemm_core(
    const u16* __restrict__ A, const u16* __restrict__ Bw,
    int N, int K, int nbase, int rowbase, u16* sB, f32x4 acc[MF][4])
{
    const int tid = threadIdx.x, w = tid >> 6, l = tid & 63;
    const int g = l >> 4, q = l & 15;
    const u16* Arow = A + (size_t)(rowbase + w * (MF * 16) + q) * K + g * 8;

    const int sbr = tid >> 3, sseg = tid & 7;
    const size_t bsrc0 = (size_t)(nbase + sbr) * K + sseg * 8;
    const size_t bsrc1 = (size_t)(nbase + sbr + 32) * K + sseg * 8;
    const int d0 = sbr * 128 + ((sseg * 16) ^ ((sbr & 7) << 4));
    const int d1 = d0 + 32 * 128;

    // prologue: stage chunk 0 into buf0
    {
        const uint4 r0 = *(const uint4*)(Bw + bsrc0);
        const uint4 r1 = *(const uint4*)(Bw + bsrc1);
        *(uint4*)((char*)sB + d0) = r0;
        *(uint4*)((char*)sB + d1) = r1;
    }
    const int NC = K >> 6;
    for (int c = 0; c < NC; ++c) {
        __syncthreads();
        char* sBc = (char*)sB + (c & 1) * 8192;
        char* sBn = (char*)sB + ((c + 1) & 1) * 8192;
        uint4 p0, p1;
        if (c + 1 < NC) {
            p0 = *(const uint4*)(Bw + bsrc0 + (c + 1) * 64);
            p1 = *(const uint4*)(Bw + bsrc1 + (c + 1) * 64);
        }
        const int kk = c * 64;
        #pragma unroll
        for (int ks = 0; ks < 2; ++ks) {
            bf16x8 af[MF];
            #pragma unroll
            for (int m = 0; m < MF; ++m)
                af[m] = *(const bf16x8*)(Arow + (size_t)m * 16 * K + kk + ks * 32);
            #pragma unroll
            for (int n = 0; n < 4; ++n) {
                const int rr = n * 16 + q;
                const bf16x8 bf = *(const bf16x8*)(
                    sBc + rr * 128 + ((ks * 64 + g * 16) ^ ((rr & 7) << 4)));
                #pragma unroll
                for (int m = 0; m < MF; ++m)
                    acc[m][n] = __builtin_amdgcn_mfma_f32_16x16x32_bf16(bf, af[m], acc[m][n], 0, 0, 0);
            }
        }
        if (c + 1 < NC) {
            *(uint4*)(sBn + d0) = p0;
            *(uint4*)(sBn + d1) = p1;
        }
    }
}

// ---------------------------------------------------------------------------
// QKV GEMM (tile 128x64): head-contiguous epilogue -> Qh/Kh [BH,S,32], Vt [BH,32,S].
// grid (64, 12).
// ---------------------------------------------------------------------------
__global__ __launch_bounds__(256) void gemm_qkv(
    const u16* __restrict__ A, const u16* __restrict__ Bw,
    const float* __restrict__ bias,
    u16* __restrict__ Qh, u16* __restrict__ Kh, u16* __restrict__ Vt)
{
    __shared__ u16 sB[2][64 * 64];
    const int tid = threadIdx.x, w = tid >> 6, l = tid & 63;
    const int g = l >> 4, q = l & 15;
    const int rowbase = blockIdx.x * 128, nbase = blockIdx.y * 64;
    f32x4 acc[2][4] = {};
    gemm_core<2>(A, Bw, 768, 256, nbase, rowbase, &sB[0][0], acc);

    #pragma unroll
    for (int m = 0; m < 2; ++m) {
        const int row = rowbase + w * 32 + m * 16 + q;
        const int s = row >> 3, b = row & 7;
        if (nbase < 512) {
            u16* dst = (nbase >= 256) ? Kh : Qh;
            #pragma unroll
            for (int n = 0; n < 4; ++n) {
                const int col = nbase + n * 16 + g * 4;
                const float4 bv = *(const float4*)(bias + col);
                const int cc = col & 255, h = cc >> 5, hd = cc & 31;
                const int bh = b * 8 + h;
                uint2 pk;
                pk.x = (unsigned)f2b(acc[m][n][0] + bv.x) | ((unsigned)f2b(acc[m][n][1] + bv.y) << 16);
                pk.y = (unsigned)f2b(acc[m][n][2] + bv.z) | ((unsigned)f2b(acc[m][n][3] + bv.w) << 16);
                *(uint2*)(dst + ((size_t)bh * S_LEN + s) * HDIM + hd) = pk;
            }
        } else {
            #pragma unroll
            for (int n = 0; n < 4; ++n) {
                const int col = nbase + n * 16 + g * 4;
                const float4 bv = *(const float4*)(bias + col);
                const int cc = col - 512, h = cc >> 5, hd = cc & 31;
                const int bh = b * 8 + h;
                Vt[((size_t)bh * HDIM + hd + 0) * S_LEN + s] = f2b(acc[m][n][0] + bv.x);
                Vt[((size_t)bh * HDIM + hd + 1) * S_LEN + s] = f2b(acc[m][n][1] + bv.y);
                Vt[((size_t)bh * HDIM + hd + 2) * S_LEN + s] = f2b(acc[m][n][2] + bv.z);
                Vt[((size_t)bh * HDIM + hd + 3) * S_LEN + s] = f2b(acc[m][n][3] + bv.w);
            }
        }
    }
}

// ---------------------------------------------------------------------------
// FFN GEMMs. MODE 2: +bias, relu -> bf16 (MF=2, tile 128x64).
//            MODE 3: +bias+resid -> f32  (MF=1, tile 64x64).
// ---------------------------------------------------------------------------
template <int MODE, int MF>
__global__ __launch_bounds__(256) void gemm_nt(
    const u16* __restrict__ A, const u16* __restrict__ Bw,
    const float* __restrict__ bias, const float* __restrict__ resid,
    float* __restrict__ outf, u16* __restrict__ outb,
    int N, int K)
{
    __shared__ u16 sB[2][64 * 64];
    const int tid = threadIdx.x, w = tid >> 6, l = tid & 63;
    const int g = l >> 4, q = l & 15;
    const int rowbase = blockIdx.x * (MF * 64), nbase = blockIdx.y * 64;
    f32x4 acc[MF][4] = {};
    gemm_core<MF>(A, Bw, N, K, nbase, rowbase, &sB[0][0], acc);

    #pragma unroll
    for (int m = 0; m < MF; ++m) {
        const int row = rowbase + w * (MF * 16) + m * 16 + q;
        #pragma unroll
        for (int n = 0; n < 4; ++n) {
            const int col = nbase + n * 16 + g * 4;
            const float4 bv = *(const float4*)(bias + col);
            float v0 = acc[m][n][0] + bv.x, v1 = acc[m][n][1] + bv.y;
            float v2 = acc[m][n][2] + bv.z, v3 = acc[m][n][3] + bv.w;
            if (MODE == 2) {
                v0 = fmaxf(v0, 0.f); v1 = fmaxf(v1, 0.f);
                v2 = fmaxf(v2, 0.f); v3 = fmaxf(v3, 0.f);
                uint2 pk;
                pk.x = (unsigned)f2b(v0) | ((unsigned)f2b(v1) << 16);
                pk.y = (unsigned)f2b(v2) | ((unsigned)f2b(v3) << 16);
                *(uint2*)(outb + (size_t)row * N + col) = pk;
            } else {
                const float4 rv = *(const float4*)(resid + (size_t)row * N + col);
                *(float4*)(outf + (size_t)row * N + col) =
                    make_float4(v0 + rv.x, v1 + rv.y, v2 + rv.z, v3 + rv.w);
            }
        }
    }
}

// ---------------------------------------------------------------------------
// Flash attention: LDS-staged K/V in MFMA-fragment order (conflict-free b128,
// double-buffered, async-split), lane-local softmax, pipelined nontemporal
// bias stream. grid (S/64, B*H), 256 thr (4 waves x 16 q-rows).
// ---------------------------------------------------------------------------
__global__ __launch_bounds__(256) void attn_kernel(
    const u16* __restrict__ Qh, const u16* __restrict__ Kh,
    const u16* __restrict__ Vt, const float* __restrict__ bias,
    u16* __restrict__ ctx)
{
    __shared__ u16 sK[2][64 * 32];
    __shared__ u16 sV[2][32 * 64];
    __shared__ u16 sP[4][16 * 64];
    const int tid = threadIdx.x, w = tid >> 6, l = tid & 63;
    const int g = l >> 4, q = l & 15;
    const int bh = blockIdx.y, b = bh >> 3, h = bh & 7;
    const int qbase = blockIdx.x * 64 + w * 16;
    const int qrow = qbase + q;

    const bf16x8 qf = *(const bf16x8*)(Qh + ((size_t)bh * S_LEN + qrow) * HDIM + g * 8);
    const float* brow = bias + ((size_t)bh * S_LEN + qrow) * S_LEN;
    u16* Pw = sP[w];
    const int swz = (q & 7) << 4;

    const u16* KsrcBase = Kh + ((size_t)bh * S_LEN + w * 16 + q) * HDIM + g * 8;
    const u16* VsrcBase = Vt + ((size_t)bh * HDIM + (w & 1) * 16 + q) * S_LEN
                             + (w >> 1) * 32 + g * 8;
    u16* KdstA = &sK[0][tid * 8]; u16* KdstB = &sK[1][tid * 8];
    u16* VdstA = &sV[0][tid * 8]; u16* VdstB = &sV[1][tid * 8];

    f32x4 ctxa[2] = {{0,0,0,0},{0,0,0,0}};
    float m = -1e30f, lsum = 0.f;

    auto loadB = [&](int kt, f32x4* bv) {
        #pragma unroll
        for (int n = 0; n < 4; ++n)
            bv[n] = __builtin_nontemporal_load(
                (const f32x4*)(brow + kt * 64 + n * 16 + g * 4));
    };

    auto proc = [&](int buf, const f32x4* bv) {
        f32x4 sc[4];
        #pragma unroll
        for (int n = 0; n < 4; ++n) {
            const bf16x8 kf = *(const bf16x8*)(&sK[buf][(n * 64 + l) * 8]);
            f32x4 z = {0, 0, 0, 0};
            sc[n] = __builtin_amdgcn_mfma_f32_16x16x32_bf16(kf, qf, z, 0, 0, 0);
        }
        #pragma unroll
        for (int n = 0; n < 4; ++n)
            #pragma unroll
            for (int r = 0; r < 4; ++r) sc[n][r] += bv[n][r];

        float mx = sc[0][0];
        #pragma unroll
        for (int n = 0; n < 4; ++n)
            #pragma unroll
            for (int r = 0; r < 4; ++r) mx = fmaxf(mx, sc[n][r]);
        mx = fmaxf(mx, __shfl_xor(mx, 16));
        mx = fmaxf(mx, __shfl_xor(mx, 32));
        const float mn = fmaxf(m, mx);
        const float corr = __expf(m - mn);
        float su = 0.f;
        u16 pb[16];
        #pragma unroll
        for (int n = 0; n < 4; ++n)
            #pragma unroll
            for (int r = 0; r < 4; ++r) {
                const float pv = __expf(sc[n][r] - mn);
                su += pv;
                pb[n * 4 + r] = f2b(pv);
            }
        su += __shfl_xor(su, 16);
        su += __shfl_xor(su, 32);
        lsum = lsum * corr + su;
        m = mn;
        #pragma unroll
        for (int jg = 0; jg < 2; ++jg)
            #pragma unroll
            for (int r = 0; r < 4; ++r) ctxa[jg][r] *= corr;

        #pragma unroll
        for (int n = 0; n < 4; ++n) {
            uint2 pk;
            pk.x = (unsigned)pb[n * 4] | ((unsigned)pb[n * 4 + 1] << 16);
            pk.y = (unsigned)pb[n * 4 + 2] | ((unsigned)pb[n * 4 + 3] << 16);
            *(uint2*)((char*)Pw + q * 128 + ((n * 32 + g * 8) ^ swz)) = pk;
        }

        #pragma unroll
        for (int ks = 0; ks < 2; ++ks) {
            const bf16x8 pf = *(const bf16x8*)((char*)Pw + q * 128 + ((ks * 64 + g * 16) ^ swz));
            #pragma unroll
            for (int jg = 0; jg < 2; ++jg) {
                const bf16x8 vf = *(const bf16x8*)(&sV[buf][((ks * 2 + jg) * 64 + l) * 8]);
                ctxa[jg] = __builtin_amdgcn_mfma_f32_16x16x32_bf16(vf, pf, ctxa[jg], 0, 0, 0);
            }
        }
    };

    f32x4 bv0[4], bv1[4];
    {
        const uint4 kr = *(const uint4*)(KsrcBase);
        const uint4 vr = *(const uint4*)(VsrcBase);
        *(uint4*)KdstA = kr;
        *(uint4*)VdstA = vr;
        loadB(0, bv0);
    }
    __syncthreads();

    for (int kt = 0; kt < 16; kt += 2) {
        {
            uint4 kr, vr;
            kr = *(const uint4*)(KsrcBase + (size_t)(kt + 1) * 64 * HDIM);
            vr = *(const uint4*)(VsrcBase + (size_t)(kt + 1) * 64);
            loadB(kt + 1, bv1);
            proc(0, bv0);
            *(uint4*)KdstB = kr;
            *(uint4*)VdstB = vr;
        }
        __syncthreads();
        {
            uint4 kr, vr;
            if (kt + 2 < 16) {
                kr = *(const uint4*)(KsrcBase + (size_t)(kt + 2) * 64 * HDIM);
                vr = *(const uint4*)(VsrcBase + (size_t)(kt + 2) * 64);
                loadB(kt + 2, bv0);
            }
            proc(1, bv1);
            if (kt + 2 < 16) {
                *(uint4*)KdstA = kr;
                *(uint4*)VdstA = vr;
            }
        }
        __syncthreads();
    }

    const float inv = 1.0f / lsum;
    #pragma unroll
    for (int jg = 0; jg < 2; ++jg) {
        uint2 pk;
        pk.x = (unsigned)f2b(ctxa[jg][0] * inv) | ((unsigned)f2b(ctxa[jg][1] * inv) << 16);
        pk.y = (unsigned)f2b(ctxa[jg][2] * inv) | ((unsigned)f2b(ctxa[jg][3] * inv) << 16);
        *(uint2*)(ctx + ((size_t)qrow * 8 + b) * DMODEL + h * 32 + jg * 16 + g * 4) = pk;
    }
}

// ---------------------------------------------------------------------------
// Fused out-proj + residual(xf) + LayerNorm2 -> yf (f32), yb (bf16).
// ---------------------------------------------------------------------------
__global__ __launch_bounds__(256) void oproj_ln(
    const u16* __restrict__ ctx, const u16* __restrict__ wob,
    const float* __restrict__ ob, const float* __restrict__ xf,
    const float* __restrict__ g2, const float* __restrict__ be2,
    float* __restrict__ yf, u16* __restrict__ yb)
{
    __shared__ float s1[4][16], s2[4][16];
    const int tid = threadIdx.x, wv = tid >> 6, l = tid & 63;
    const int g = l >> 4, q = l & 15;
    const int row = blockIdx.x * 16 + q;
    f32x4 acc[4] = {{0,0,0,0},{0,0,0,0},{0,0,0,0},{0,0,0,0}};
    const u16* Arow = ctx + (size_t)row * 256 + g * 8;
    const u16* Brow = wob + (size_t)(wv * 64 + q) * 256 + g * 8;

    #pragma unroll 2
    for (int kk = 0; kk < 256; kk += 32) {
        const bf16x8 af = *(const bf16x8*)(Arow + kk);
        #pragma unroll
        for (int n = 0; n < 4; ++n) {
            const bf16x8 bf = *(const bf16x8*)(Brow + (size_t)n * 16 * 256 + kk);
            acc[n] = __builtin_amdgcn_mfma_f32_16x16x32_bf16(bf, af, acc[n], 0, 0, 0);
        }
    }

    float sum = 0.f;
    #pragma unroll
    for (int n = 0; n < 4; ++n) {
        const int col = wv * 64 + n * 16 + g * 4;
        const float4 bv = *(const float4*)(ob + col);
        const float4 rv = *(const float4*)(xf + (size_t)row * 256 + col);
        acc[n][0] += bv.x + rv.x; acc[n][1] += bv.y + rv.y;
        acc[n][2] += bv.z + rv.z; acc[n][3] += bv.w + rv.w;
        sum += acc[n][0] + acc[n][1] + acc[n][2] + acc[n][3];
    }
    sum += __shfl_xor(sum, 16);
    sum += __shfl_xor(sum, 32);
    if (l < 16) s1[wv][q] = sum;
    __syncthreads();
    const float mu = (s1[0][q] + s1[1][q] + s1[2][q] + s1[3][q]) * (1.0f / 256);
    float sq = 0.f;
    #pragma unroll
    for (int n = 0; n < 4; ++n)
        #pragma unroll
        for (int r = 0; r < 4; ++r) {
            const float d = acc[n][r] - mu;
            sq += d * d;
        }
    sq += __shfl_xor(sq, 16);
    sq += __shfl_xor(sq, 32);
    if (l < 16) s2[wv][q] = sq;
    __syncthreads();
    const float rs = rsqrtf((s2[0][q] + s2[1][q] + s2[2][q] + s2[3][q]) * (1.0f / 256) + 1e-5f);

    #pragma unroll
    for (int n = 0; n < 4; ++n) {
        const int col = wv * 64 + n * 16 + g * 4;
        const float4 gv = *(const float4*)(g2 + col);
        const float4 b2 = *(const float4*)(be2 + col);
        const float y0 = (acc[n][0] - mu) * rs * gv.x + b2.x;
        const float y1 = (acc[n][1] - mu) * rs * gv.y + b2.y;
        const float y2 = (acc[n][2] - mu) * rs * gv.z + b2.z;
        const float y3 = (acc[n][3] - mu) * rs * gv.w + b2.w;
        *(float4*)(yf + (size_t)row * 256 + col) = make_float4(y0, y1, y2, y3);
        uint2 pk;
        pk.x = (unsigned)f2b(y0) | ((unsigned)f2b(y1) << 16);
        pk.y = (unsigned)f2b(y2) | ((unsigned)f2b(y3) << 16);
        *(uint2*)(yb + (size_t)row * 256 + col) = pk;
    }
}

// ---------------------------------------------------------------------------
extern "C" void kernel_launch(void* const* d_in, const int* in_sizes, int n_in,
                              void* d_out, int out_size, void* d_ws, size_t ws_size,
                              hipStream_t stream)
{
    const float* src  = (const float*)d_in[0];
    const float* bias = (const float*)d_in[1];
    const float* ipw  = (const float*)d_in[2];
    const float* ipb  = (const float*)d_in[3];
    const float* outw = (const float*)d_in[4];
    const float* outb = (const float*)d_in[5];
    const float* w1   = (const float*)d_in[6];
    const float* b1   = (const float*)d_in[7];
    const float* w2   = (const float*)d_in[8];
    const float* b2   = (const float*)d_in[9];
    const float* g1   = (const float*)d_in[10];
    const float* be1  = (const float*)d_in[11];
    const float* g2   = (const float*)d_in[12];
    const float* be2  = (const float*)d_in[13];

    char* p = (char*)d_ws;
    auto alloc = [&](size_t bytes) -> void* {
        void* r = (void*)p;
        p += (bytes + 255) & ~(size_t)255;
        return r;
    };
    float* xf   = (float*)alloc((size_t)NROWS * DMODEL * 4);
    u16*   xb   = (u16*)  alloc((size_t)NROWS * DMODEL * 2);
    u16*   Qh   = (u16*)  alloc((size_t)64 * S_LEN * HDIM * 2);
    u16*   Kb   = (u16*)  alloc((size_t)64 * S_LEN * HDIM * 2);
    u16*   Vt   = (u16*)  alloc((size_t)64 * S_LEN * HDIM * 2);
    u16*   ctx  = (u16*)  alloc((size_t)NROWS * DMODEL * 2);
    float* yf   = (float*)alloc((size_t)NROWS * DMODEL * 4);
    u16*   yb   = (u16*)  alloc((size_t)NROWS * DMODEL * 2);
    u16*   hb   = (u16*)  alloc((size_t)NROWS * DFF * 2);
    u16*   wqkv = (u16*)  alloc((size_t)768 * 256 * 2);
    u16*   wob  = (u16*)  alloc((size_t)256 * 256 * 2);
    u16*   w1b  = (u16*)  alloc((size_t)1024 * 256 * 2);
    u16*   w2b  = (u16*)  alloc((size_t)256 * 1024 * 2);
    float* bq   = (float*)alloc(768 * 4);

    prep_kernel<<<2816, 256, 0, stream>>>(src, g1, be1, xf, xb,
                                          ipw, outw, w1, w2, ipb,
                                          wqkv, wob, w1b, w2b, bq);
    gemm_qkv<<<dim3(64, 12), 256, 0, stream>>>(xb, wqkv, bq, Qh, Kb, Vt);
    attn_kernel<<<dim3(16, 64), 256, 0, stream>>>(Qh, Kb, Vt, bias, ctx);
    oproj_ln<<<512, 256, 0, stream>>>(ctx, wob, outb, xf, g2, be2, yf, yb);
    gemm_nt<2, 2><<<dim3(64, 16), 256, 0, stream>>>(yb, w1b, b1, nullptr, nullptr, hb, 1024, 256);
    gemm_nt<3, 1><<<dim3(128, 4), 256, 0, stream>>>(hb, w2b, b2, yf, (float*)d_out, nullptr, 256, 1024);
}